// Round 18
// baseline (262.447 us; speedup 1.0000x reference)
//
#include <hip/hip_runtime.h>
#include <math.h>

#define SEQ 1024
#define DMODEL 768
#define NHEADS 12
#define HDIM 64
#define D3 2304
#define BH 48            // BATCH*NHEADS
#define NTOK 4096        // BATCH*SEQ
#define KTH 104857u      // int(1024*1024*0.1)
#define NBIN 4096        // exact-bf16 hist: patterns 14336..18431 (full mantissa)
#define BIN0 14336       // bf16 pattern of 2^-15

typedef __bf16 bf16x8 __attribute__((ext_vector_type(8)));
typedef float  f32x4  __attribute__((ext_vector_type(4)));

// swizzled LDS offset (ushort units) for 64B-row tiles (GEMM core + V tile)
#define SWZ(row, chunk) ((row) * 32 + (((chunk) ^ (((row) >> 1) & 3)) * 8))

// async global->LDS, 16B per lane, linear dest (wave-uniform base + lane*16)
__device__ __forceinline__ void gl16(const ushort* g, ushort* l) {
    __builtin_amdgcn_global_load_lds(
        (__attribute__((address_space(1))) void*)(size_t)(g),
        (__attribute__((address_space(3))) void*)(l), 16, 0, 0);
}

// ---------------- fp32 -> (bf16 hi, bf16 lo) split, RNE ----------------
__device__ __forceinline__ void split1(float x, ushort& h, ushort& l) {
    unsigned b  = __float_as_uint(x);
    unsigned hb = (b + 0x7FFFu + ((b >> 16) & 1u)) >> 16;   // RNE to bf16
    float hf = __uint_as_float(hb << 16);
    float r  = x - hf;
    unsigned rb = __float_as_uint(r);
    unsigned lb = (rb + 0x7FFFu + ((rb >> 16) & 1u)) >> 16;
    h = (ushort)hb; l = (ushort)lb;
}

__device__ __forceinline__ ushort bf16rne(float x) {
    unsigned b = __float_as_uint(x);
    return (ushort)((b + 0x7FFFu + ((b >> 16) & 1u)) >> 16);
}

// ---------------- fused prep: x-split (+hist zero) | Wqkv wsplit | Wout wsplit
__global__ __launch_bounds__(256) void k_prep(
    const float* __restrict__ x, ushort* __restrict__ xh,
    ushort* __restrict__ xl, int n, unsigned* __restrict__ hist,
    const float* __restrict__ Wqkv, ushort* __restrict__ Wqth,
    ushort* __restrict__ Wqtl,
    const float* __restrict__ Wout, ushort* __restrict__ Woth,
    ushort* __restrict__ Wotl) {
    __shared__ float t[64][65];
    int bx = blockIdx.x, tid = threadIdx.x;
    if (bx < 3072) {
        int g = bx * 256 + tid;
        if (g < BH * NBIN) hist[g] = 0u;
        int i = g * 4;
        if (i >= n) return;
        float4 v = *(const float4*)(x + i);
        ushort4 hh, ll;
        split1(v.x, hh.x, ll.x); split1(v.y, hh.y, ll.y);
        split1(v.z, hh.z, ll.z); split1(v.w, hh.w, ll.w);
        *(ushort4*)(xh + i) = hh;
        *(ushort4*)(xl + i) = ll;
        return;
    }
    const float* W; ushort* Wth; ushort* Wtl; int N, n0, k0;
    if (bx < 3504) {
        int b2 = bx - 3072;
        W = Wqkv; Wth = Wqth; Wtl = Wqtl; N = D3;
        n0 = (b2 % 36) * 64; k0 = (b2 / 36) * 64;
    } else {
        int b2 = bx - 3504;
        W = Wout; Wth = Woth; Wtl = Wotl; N = DMODEL;
        n0 = (b2 % 12) * 64; k0 = (b2 / 12) * 64;
    }
    const int K = DMODEL;
    int r = tid >> 4, c = (tid & 15) * 4;
#pragma unroll
    for (int u = 0; u < 4; u++) {
        int rr = r + u * 16;
        float4 v = *(const float4*)(W + (size_t)(k0 + rr) * N + n0 + c);
        t[rr][c] = v.x; t[rr][c + 1] = v.y; t[rr][c + 2] = v.z; t[rr][c + 3] = v.w;
    }
    __syncthreads();
    int nn = tid >> 2, kc = (tid & 3) * 16;
    ushort hb[16] __attribute__((aligned(16)));
    ushort lb[16] __attribute__((aligned(16)));
#pragma unroll
    for (int j = 0; j < 16; j++) split1(t[kc + j][nn], hb[j], lb[j]);
    ushort* dh = Wth + (size_t)(n0 + nn) * K + k0 + kc;
    ushort* dl = Wtl + (size_t)(n0 + nn) * K + k0 + kc;
    *(uint4*)(dh)     = *(uint4*)&hb[0];
    *(uint4*)(dh + 8) = *(uint4*)&hb[8];
    *(uint4*)(dl)     = *(uint4*)&lb[0];
    *(uint4*)(dl + 8) = *(uint4*)&lb[8];
}

// ======================================================================
// bf16x3 GEMM core v3: BM=128, BN=128, BK=32, 256 thr, DOUBLE-BUFFERED
// LDS (64 KB) with ONE barrier per K-step:
//   STAGE(buf^1, k+1) -> ds_read frags(buf) -> MFMA -> barrier.
// Staging issues BEFORE the MFMA window, so the barrier's vmcnt(0) drain
// finds loads complete (attacks the m97 ~20% drain stall). Grid-limited
// to ~2.25 blocks/CU, so 64 KB LDS costs no occupancy. Write-after-read:
// next iter stages into [cur], which all waves finished reading before
// this iter's barrier. No s_setprio (r16: regression on lockstep GEMM).
// ======================================================================
#define STAGE_LDS(buf, ko)                                                      \
    gl16(gAh + (ko), &sA[buf][0][wbase]);                                       \
    gl16(gAh2 + (ko), &sA[buf][0][2048 + wbase]);                               \
    gl16(gAl + (ko), &sA[buf][1][wbase]);                                       \
    gl16(gAl2 + (ko), &sA[buf][1][2048 + wbase]);                               \
    gl16(gBh + (ko), &sB[buf][0][wbase]);                                       \
    gl16(gBh2 + (ko), &sB[buf][0][2048 + wbase]);                               \
    gl16(gBl + (ko), &sB[buf][1][wbase]);                                       \
    gl16(gBl2 + (ko), &sB[buf][1][2048 + wbase]);

#define GEMM_CORE_SETUP(Kdim)                                                   \
    __shared__ ushort sA[2][2][128 * 32];                                       \
    __shared__ ushort sB[2][2][128 * 32];                                       \
    int tid = threadIdx.x, lane = tid & 63, wave = tid >> 6;                    \
    int wm = (wave >> 1) * 64, wn = (wave & 1) * 64;                            \
    int l15 = lane & 15, q = lane >> 4;                                         \
    int sr = tid >> 2, sc = tid & 3;                                            \
    const int K = (Kdim);                                                       \
    int scs = sc ^ ((sr >> 1) & 3);   /* inverse-swizzled source chunk */       \
    const ushort* gAh = Ah + (size_t)(m0 + sr) * K + scs * 8;                   \
    const ushort* gAl = Al + (size_t)(m0 + sr) * K + scs * 8;                   \
    const ushort* gBh = Bh + (size_t)(n0 + sr) * K + scs * 8;                   \
    const ushort* gBl = Bl + (size_t)(n0 + sr) * K + scs * 8;                   \
    const ushort* gAh2 = gAh + (size_t)64 * K;                                  \
    const ushort* gAl2 = gAl + (size_t)64 * K;                                  \
    const ushort* gBh2 = gBh + (size_t)64 * K;                                  \
    const ushort* gBl2 = gBl + (size_t)64 * K;                                  \
    int wbase = wave * 512;           /* 1024 B per wave, lane l -> +16B*l */   \
    f32x4 acc[4][4] = {};                                                       \
    STAGE_LDS(0, 0)                                                             \
    __syncthreads();                                                            \
    const int NIT = K / 32;                                                     \
    for (int it = 0; it < NIT; ++it) {                                          \
        int cur = it & 1;                                                       \
        if (it + 1 < NIT) { STAGE_LDS(cur ^ 1, (it + 1) * 32) }                 \
        bf16x8 fah[4], fal[4], fbh[4], fbl[4];                                  \
        _Pragma("unroll")                                                       \
        for (int mt = 0; mt < 4; mt++) {                                        \
            int rr = wm + mt * 16 + l15;                                        \
            fah[mt] = *(const bf16x8*)(&sA[cur][0][SWZ(rr, q)]);                \
            fal[mt] = *(const bf16x8*)(&sA[cur][1][SWZ(rr, q)]);                \
        }                                                                       \
        _Pragma("unroll")                                                       \
        for (int nt = 0; nt < 4; nt++) {                                        \
            int rr = wn + nt * 16 + l15;                                        \
            fbh[nt] = *(const bf16x8*)(&sB[cur][0][SWZ(rr, q)]);                \
            fbl[nt] = *(const bf16x8*)(&sB[cur][1][SWZ(rr, q)]);                \
        }                                                                       \
        _Pragma("unroll")                                                       \
        for (int mt = 0; mt < 4; mt++)                                          \
            _Pragma("unroll")                                                   \
            for (int nt = 0; nt < 4; nt++) {                                    \
                acc[mt][nt] = __builtin_amdgcn_mfma_f32_16x16x32_bf16(          \
                    fah[mt], fbh[nt], acc[mt][nt], 0, 0, 0);                    \
                acc[mt][nt] = __builtin_amdgcn_mfma_f32_16x16x32_bf16(          \
                    fah[mt], fbl[nt], acc[mt][nt], 0, 0, 0);                    \
                acc[mt][nt] = __builtin_amdgcn_mfma_f32_16x16x32_bf16(          \
                    fal[mt], fbh[nt], acc[mt][nt], 0, 0, 0);                    \
            }                                                                   \
        __syncthreads();   /* drains staged loads; frees [cur] for next stage */\
    }

// ---------------- out-proj GEMM: C = A@B + bias (fp32 out) ----------------
// 1D grid 192, XCD-chunked: xcd owns 8m x 3n region (L2 panel reuse).
__global__ __launch_bounds__(256) void k_gemm_out(
    const ushort* __restrict__ Ah, const ushort* __restrict__ Al,
    const ushort* __restrict__ Bh, const ushort* __restrict__ Bl,
    const float* __restrict__ bias, float* __restrict__ C,
    int M, int N, int Kin) {
    int orig = blockIdx.x;
    int xcd = orig & 7, local = orig >> 3;      // 24 blocks per XCD
    int mslab = xcd >> 1, nhalf = xcd & 1;
    int ml = local / 3, nl = local % 3;         // 8m x 3n region
    int m0 = (mslab * 8 + ml) * 128;
    int n0 = (nhalf * 3 + nl) * 128;
    GEMM_CORE_SETUP(Kin)
#pragma unroll
    for (int nt = 0; nt < 4; nt++) {
        int col = n0 + wn + nt * 16 + l15;
        float bv = bias[col];
#pragma unroll
        for (int mt = 0; mt < 4; mt++) {
            int rowb = m0 + wm + mt * 16 + q * 4;
#pragma unroll
            for (int r = 0; r < 4; r++)
                C[(size_t)(rowb + r) * N + col] = acc[mt][nt][r] + bv;
        }
    }
}

// ---------------- QKV GEMM: epilogue writes split Q/K straight + V(hi) transposed
// 1D grid 576, XCD-chunked: xcd owns 8m x 9n region (FETCH 71.8 -> 29.6MB, r17).
__global__ __launch_bounds__(256) void k_gemm_qkv(
    const ushort* __restrict__ Ah, const ushort* __restrict__ Al,
    const ushort* __restrict__ Bh, const ushort* __restrict__ Bl,
    const float* __restrict__ bias,
    ushort* __restrict__ Qh, ushort* __restrict__ Ql,
    ushort* __restrict__ Kh, ushort* __restrict__ Kl,
    ushort* __restrict__ Vth) {
    int orig = blockIdx.x;
    int xcd = orig & 7, local = orig >> 3;      // 72 blocks per XCD
    int mslab = xcd >> 1, nhalf = xcd & 1;
    int ml = local / 9, nl = local % 9;         // 8m x 9n region
    int m0 = (mslab * 8 + ml) * 128;
    int n0 = (nhalf * 9 + nl) * 128;
    GEMM_CORE_SETUP(DMODEL)
    int region = n0 / 768;    // 0=Q, 1=K, 2=V (uniform per block: 128 | 768)
#pragma unroll
    for (int nt = 0; nt < 4; nt++) {
        int col = n0 + wn + nt * 16 + l15;
        float bv = bias[col];
        int cin = col - region * 768;
        int h = cin >> 6, d = cin & 63;
#pragma unroll
        for (int mt = 0; mt < 4; mt++) {
            int rowb = m0 + wm + mt * 16 + q * 4;
            int b = rowb >> 10;
            int s0 = rowb & 1023;
            int bh = b * NHEADS + h;
            if (region == 2) {
                ushort h4[4] __attribute__((aligned(8)));
#pragma unroll
                for (int r = 0; r < 4; r++)
                    h4[r] = bf16rne(acc[mt][nt][r] + bv);
                size_t off = ((size_t)(bh * 64 + d) << 10) + s0;
                *(ushort4*)(Vth + off) = *(ushort4*)h4;
            } else {
                ushort* Ph = region ? Kh : Qh;
                ushort* Pl = region ? Kl : Ql;
                size_t off = ((size_t)((bh << 10) + s0)) * 64 + d;
#pragma unroll
                for (int r = 0; r < 4; r++) {
                    ushort hs, ls;
                    split1(acc[mt][nt][r] + bv, hs, ls);
                    Ph[off + (size_t)r * 64] = hs;
                    Pl[off + (size_t)r * 64] = ls;
                }
            }
        }
    }
}

// ---------------- scores v2: HIST-ONLY, 128-i x 512-j per block ---------------
// grid 768 (XCD-chunked: 8*96, each XCD owns 6 whole bh). Flattened 16-step
// K-pipeline; per-element S accumulation order identical -> threshold bit-exact.
__global__ __launch_bounds__(256) void k_scores(
    const ushort* __restrict__ Qh, const ushort* __restrict__ Ql,
    const ushort* __restrict__ Kh, const ushort* __restrict__ Kl,
    unsigned* __restrict__ hist) {
    __shared__ unsigned lh[NBIN];
    int orig = blockIdx.x;
    int wid = (orig & 7) * 96 + (orig >> 3);   // bijective: 768 = 8*96
    int bh = wid >> 4;
    int rem = wid & 15;
    int i0 = (rem >> 1) * 128;
    int j0b = (rem & 1) * 512;
    int tid = threadIdx.x, lane = tid & 63, wave = tid >> 6;
    int l15 = lane & 15, q = lane >> 4;
    int wj = (wave >> 1) * 64, wi = (wave & 1) * 64;   // j = M-dim, i = N-dim
    for (int i = tid; i < NBIN; i += 256) lh[i] = 0u;
    __syncthreads();   // lh ready; no further block-wide sync until flush

    const ushort* qb  = Qh + ((size_t)bh << 16);
    const ushort* qlb = Ql + ((size_t)bh << 16);
    const ushort* kb  = Kh + ((size_t)bh << 16);
    const ushort* klb = Kl + ((size_t)bh << 16);

    bf16x8 fqh[4][2], fql[4][2];
#pragma unroll
    for (int nt = 0; nt < 4; nt++)
#pragma unroll
        for (int kk = 0; kk < 2; kk++) {
            size_t off = (size_t)(i0 + wi + nt * 16 + l15) * 64 + kk * 32 + q * 8;
            fqh[nt][kk] = *(const bf16x8*)(qb + off);
            fql[nt][kk] = *(const bf16x8*)(qlb + off);
        }
    bf16x8 fkh[2][2], fkl[2][2];
    {   // prologue: step 0's K frags (j-row = j0b + wj)
        size_t off = (size_t)(j0b + wj + l15) * 64 + q * 8;
        fkh[0][0] = *(const bf16x8*)(kb + off);
        fkl[0][0] = *(const bf16x8*)(klb + off);
        fkh[0][1] = *(const bf16x8*)(kb + off + 32);
        fkl[0][1] = *(const bf16x8*)(klb + off + 32);
    }

#pragma unroll
    for (int s = 0; s < 16; s++) {
        int cur = s & 1;
        if (s + 1 < 16) {   // prefetch next step's K frags (crosses j-tiles)
            int s1 = s + 1;
            int jr = j0b + (s1 >> 2) * 128 + wj + (s1 & 3) * 16;
            size_t off = (size_t)(jr + l15) * 64 + q * 8;
            fkh[cur ^ 1][0] = *(const bf16x8*)(kb + off);
            fkl[cur ^ 1][0] = *(const bf16x8*)(klb + off);
            fkh[cur ^ 1][1] = *(const bf16x8*)(kb + off + 32);
            fkl[cur ^ 1][1] = *(const bf16x8*)(klb + off + 32);
        }
        f32x4 acc[4] = {};
        __builtin_amdgcn_s_setprio(1);
#pragma unroll
        for (int kk = 0; kk < 2; kk++)
#pragma unroll
            for (int nt = 0; nt < 4; nt++) {
                acc[nt] = __builtin_amdgcn_mfma_f32_16x16x32_bf16(
                    fkh[cur][kk], fqh[nt][kk], acc[nt], 0, 0, 0);
                acc[nt] = __builtin_amdgcn_mfma_f32_16x16x32_bf16(
                    fkl[cur][kk], fqh[nt][kk], acc[nt], 0, 0, 0);
                acc[nt] = __builtin_amdgcn_mfma_f32_16x16x32_bf16(
                    fkh[cur][kk], fql[nt][kk], acc[nt], 0, 0, 0);
            }
        __builtin_amdgcn_s_setprio(0);
#pragma unroll
        for (int nt = 0; nt < 4; nt++) {
#pragma unroll
            for (int r = 0; r < 4; r++) {
                ushort u = bf16rne(__expf(acc[nt][r] * 0.125f));
                int bin = (int)u - BIN0;
                bin = (bin < 0) ? 0 : ((bin > NBIN - 1) ? NBIN - 1 : bin);
                atomicAdd(&lh[bin], 1u);
            }
        }
    }
    __syncthreads();
    for (int i = tid; i < NBIN; i += 256) {
        unsigned cc = lh[i];
        if (cc) atomicAdd(&hist[bh * NBIN + i], cc);
    }
}

// ---------------- PV fused v5: wave-parallel select + LDS-staged recompute ----
__global__ __launch_bounds__(256) void k_pv(const ushort* __restrict__ Qh,
                                            const ushort* __restrict__ Ql,
                                            const ushort* __restrict__ Kh,
                                            const ushort* __restrict__ Kl,
                                            const ushort* __restrict__ Vth,
                                            const unsigned* __restrict__ hist,
                                            ushort* __restrict__ ctxh,
                                            ushort* __restrict__ ctxl) {
    __shared__ ushort sK[2][2][32 * 64];   // [buf][h/l][32 j][8 swz chunks]
    __shared__ ushort sV[2][64 * 32];      // [buf] GEMM-SWZ [64 d][32 j]
    __shared__ ushort pt[4][32 * 40] __attribute__((aligned(16)));
    __shared__ unsigned wtot[4];
    __shared__ unsigned thrS;
    int orig = blockIdx.x;
    int wid = (orig & 7) * 48 + (orig >> 3);   // bijective: 384 = 8*48
    int bh = wid >> 3;
    int i0 = (wid & 7) * 128;
    int b = bh / NHEADS, h = bh % NHEADS;
    int tid = threadIdx.x, lane = tid & 63, wave = tid >> 6;
    int l15 = lane & 15, q = lane >> 4;

    const ushort* qb  = Qh + ((size_t)bh << 16);
    const ushort* qlb = Ql + ((size_t)bh << 16);
    const ushort* kb  = Kh + ((size_t)bh << 16);
    const ushort* klb = Kl + ((size_t)bh << 16);
    const ushort* vh0 = Vth + ((size_t)bh << 16);   // [64 d][1024 j]

    // staging sources (pre-swizzled); dest is wave-uniform base + lane*16
    int sr2 = tid >> 3, sc2 = tid & 7;   // K tile coords
    const ushort* gK  = kb  + (size_t)sr2 * 64 + ((sc2 ^ (sr2 & 7)) * 8);
    const ushort* gKl = klb + (size_t)sr2 * 64 + ((sc2 ^ (sr2 & 7)) * 8);
    int sr = tid >> 2, sc = tid & 3;     // V tile coords
    const ushort* gV = vh0 + (size_t)sr * 1024 + ((sc ^ ((sr >> 1) & 3)) * 8);
    int wbase = wave * 512;

    // prologue: stage j-window 0 into buf 0 (loads fly during the select scan)
    gl16(gK,  &sK[0][0][wbase]);
    gl16(gKl, &sK[0][1][wbase]);
    gl16(gV,  &sV[0][wbase]);

    // ---- inline select, wave-parallel scan (unsigned adds -> bit-identical)
    const unsigned* hrow = hist + bh * NBIN;
    unsigned psum = 0;
#pragma unroll
    for (int i = 0; i < 16; i++) psum += hrow[tid * 16 + i];
    unsigned incl = psum;
#pragma unroll
    for (int off = 1; off < 64; off <<= 1) {
        unsigned xx = __shfl_up(incl, off, 64);
        if (lane >= off) incl += xx;
    }
    if (lane == 63) wtot[wave] = incl;
    __syncthreads();            // wtot ready (also drains prologue staging)
    unsigned base = 0;
#pragma unroll
    for (int w2 = 0; w2 < 4; w2++)
        if (w2 < wave) base += wtot[w2];
    unsigned pre = base + incl - psum;
    if (pre < KTH && pre + psum >= KTH) {
        unsigned run = pre; int d = 15;
#pragma unroll
        for (int i = 0; i < 16; i++) {
            unsigned v = hrow[tid * 16 + i];
            if (run + v >= KTH) { d = i; break; }
            run += v;
        }
        thrS = (unsigned)(BIN0 + tid * 16 + d);
    }
    __syncthreads();
    unsigned t = thrS;

    // Q frags: 2 i-groups x {kk0,kk1} x {h,l}
    bf16x8 fqh[2][2], fql[2][2];
#pragma unroll
    for (int ig = 0; ig < 2; ig++)
#pragma unroll
        for (int kk = 0; kk < 2; kk++) {
            size_t off = (size_t)(i0 + wave * 32 + ig * 16 + l15) * 64 + kk * 32 + q * 8;
            fqh[ig][kk] = *(const bf16x8*)(qb + off);
            fql[ig][kk] = *(const bf16x8*)(qlb + off);
        }

    f32x4 accp[2][4] = {};
    f32x4 lacc[2] = {};
    uint4 onesu = {0x3F803F80u, 0x3F803F80u, 0x3F803F80u, 0x3F803F80u};
    bf16x8 ones = *(bf16x8*)&onesu;
    ushort* myP = &pt[wave][0];

    for (int j0 = 0; j0 < SEQ; j0 += 32) {
        int cur = (j0 >> 5) & 1;
        // K frags from LDS (swizzled chunk lookup)
        bf16x8 kh[2][2], kl[2][2];   // [j16][kk]
#pragma unroll
        for (int j16 = 0; j16 < 2; j16++) {
            int row = j16 * 16 + l15, rs = row & 7;
#pragma unroll
            for (int kk = 0; kk < 2; kk++) {
                int off = row * 64 + (((kk * 4 + q) ^ rs) * 8);
                kh[j16][kk] = *(const bf16x8*)(&sK[cur][0][off]);
                kl[j16][kk] = *(const bf16x8*)(&sK[cur][1][off]);
            }
        }
        bf16x8 fvh[4];
#pragma unroll
        for (int nt = 0; nt < 4; nt++)
            fvh[nt] = *(const bf16x8*)(&sV[cur][SWZ(nt * 16 + l15, q)]);
        // prefetch next window while computing this one
        if (j0 + 32 < SEQ) {
            int nxt = cur ^ 1;
            gl16(gK  + (size_t)(j0 + 32) * 64, &sK[nxt][0][wbase]);
            gl16(gKl + (size_t)(j0 + 32) * 64, &sK[nxt][1][wbase]);
            gl16(gV  + (j0 + 32),              &sV[nxt][wbase]);
        }
        // QK^T (same order as k_scores) -> exp -> mask -> wave-private P-tile
        __builtin_amdgcn_s_setprio(1);
        bf16x8 pa[2];
#pragma unroll
        for (int ig = 0; ig < 2; ig++) {
#pragma unroll
            for (int j16 = 0; j16 < 2; j16++) {
                f32x4 s = {};
                s = __builtin_amdgcn_mfma_f32_16x16x32_bf16(kh[j16][0], fqh[ig][0], s, 0, 0, 0);
                s = __builtin_amdgcn_mfma_f32_16x16x32_bf16(kl[j16][0], fqh[ig][0], s, 0, 0, 0);
                s = __builtin_amdgcn_mfma_f32_16x16x32_bf16(kh[j16][0], fql[ig][0], s, 0, 0, 0);
                s = __builtin_amdgcn_mfma_f32_16x16x32_bf16(kh[j16][1], fqh[ig][1], s, 0, 0, 0);
                s = __builtin_amdgcn_mfma_f32_16x16x32_bf16(kl[j16][1], fqh[ig][1], s, 0, 0, 0);
                s = __builtin_amdgcn_mfma_f32_16x16x32_bf16(kh[j16][1], fql[ig][1], s, 0, 0, 0);
                unsigned pb[4];
#pragma unroll
                for (int r = 0; r < 4; r++) {
                    unsigned u = bf16rne(__expf(s[r] * 0.125f));
                    pb[r] = (u <= t) ? 0u : u;
                }
                uint2 w;
                w.x = pb[0] | (pb[1] << 16);
                w.y = pb[2] | (pb[3] << 16);
                *(uint2*)(&myP[(ig * 16 + l15) * 40 + j16 * 16 + q * 4]) = w;
            }
            pa[ig] = *(const bf16x8*)(&myP[(ig * 16 + l15) * 40 + q * 8]);
        }
        // PV + rowsum (V frags shared across both i-groups)
#pragma unroll
        for (int ig = 0; ig < 2; ig++) {
#pragma unroll
            for (int nt = 0; nt < 4; nt++)
                accp[ig][nt] = __builtin_amdgcn_mfma_f32_16x16x32_bf16(
                    pa[ig], fvh[nt], accp[ig][nt], 0, 0, 0);
            lacc[ig] = __builtin_amdgcn_mfma_f32_16x16x32_bf16(
                pa[ig], ones, lacc[ig], 0, 0, 0);
        }
        __builtin_amdgcn_s_setprio(0);
        __syncthreads();   // staging drained + all waves done with cur
    }
    // epilogue
#pragma unroll
    for (int ig = 0; ig < 2; ig++)
#pragma unroll
        for (int r = 0; r < 4; r++) {
            int i = i0 + wave * 32 + ig * 16 + q * 4 + r;
            float l = lacc[ig][r];
#pragma unroll
            for (int nt = 0; nt < 4; nt++) {
                int d = nt * 16 + l15;
                ushort hs, ls;
                split1(accp[ig][nt][r] / l, hs, ls);
                size_t off = ((size_t)(b * SEQ + i)) * DMODEL + h * 64 + d;
                ctxh[off] = hs;
                ctxl[off] = ls;
            }
        }
}

extern "C" void kernel_launch(void* const* d_in, const int* in_sizes, int n_in,
                              void* d_out, int out_size, void* d_ws, size_t ws_size,
                              hipStream_t stream) {
    const float* x    = (const float*)d_in[0];
    const float* Wqkv = (const float*)d_in[1];
    const float* bqkv = (const float*)d_in[2];
    const float* Wout = (const float*)d_in[3];
    const float* bout = (const float*)d_in[4];
    float* out = (float*)d_out;

    char* ws = (char*)d_ws;
    // persistent layout
    ushort* Qh  = (ushort*)(ws + 0);                 //  6,291,456
    ushort* Ql  = (ushort*)(ws + 6291456);
    ushort* Kh  = (ushort*)(ws + 12582912);
    ushort* Kl  = (ushort*)(ws + 18874368);
    ushort* Vth = (ushort*)(ws + 25165824);          //  6,291,456 (hi only)
    ushort* ctxh = (ushort*)(ws + 239075328);        //  6,291,456
    ushort* ctxl = (ushort*)(ws + 245366784);        // ends 251,658,240
    unsigned* hist = (unsigned*)(ws + 251658240);    // 48*4096*4 = 786,432
    // scratch (former P region):
    ushort* xh     = (ushort*)(ws + 37748736);                 // ends 44,040,192
    ushort* xl     = (ushort*)(ws + 37748736 + 6291456);       // ends 50,331,648
    ushort* Wqkvth = (ushort*)(ws + 37748736 + 12582912);      // ends 53,870,592
    ushort* Wqkvtl = (ushort*)(ws + 37748736 + 16121856);      // ends 57,409,536
    ushort* Woutth = (ushort*)(ws + 57409536);                 // ends 58,589,184
    ushort* Wouttl = (ushort*)(ws + 58589184);                 // ends 59,768,832

    // fused prep: x split (+hist zero) | Wqkv wsplit | Wout wsplit (1 launch)
    k_prep<<<3648, 256, 0, stream>>>(x, xh, xl, NTOK * DMODEL, hist,
                                     Wqkv, Wqkvth, Wqkvtl, Wout, Woutth, Wouttl);
    k_gemm_qkv<<<576, 256, 0, stream>>>(
        xh, xl, Wqkvth, Wqkvtl, bqkv, Qh, Ql, Kh, Kl, Vth);
    // pass 1: exact 4096-bin histogram of bf16(exp(QK^T/8)) — no P store
    k_scores<<<768, 256, 0, stream>>>(Qh, Ql, Kh, Kl, hist);
    // pass 2: fused select + recompute QK^T -> exp -> mask -> PV / rowsum
    k_pv<<<384, 256, 0, stream>>>(Qh, Ql, Kh, Kl, Vth, hist, ctxh, ctxl);
    // out = ctx @ W_out + b_out
    k_gemm_out<<<192, 256, 0, stream>>>(
        ctxh, ctxl, Woutth, Wouttl, bout, out, NTOK, DMODEL, DMODEL);
}

// Round 19
// 237.057 us; speedup vs baseline: 1.1071x; 1.1071x over previous
//
#include <hip/hip_runtime.h>
#include <math.h>

#define SEQ 1024
#define DMODEL 768
#define NHEADS 12
#define HDIM 64
#define D3 2304
#define BH 48            // BATCH*NHEADS
#define NTOK 4096        // BATCH*SEQ
#define KTH 104857u      // int(1024*1024*0.1)
#define NBIN 4096        // exact-bf16 hist: patterns 14336..18431 (full mantissa)
#define BIN0 14336       // bf16 pattern of 2^-15

typedef __bf16 bf16x8 __attribute__((ext_vector_type(8)));
typedef float  f32x4  __attribute__((ext_vector_type(4)));

// swizzled LDS offset (ushort units) for 64B-row tiles (GEMM core + V tile)
#define SWZ(row, chunk) ((row) * 32 + (((chunk) ^ (((row) >> 1) & 3)) * 8))

// async global->LDS, 16B per lane, linear dest (wave-uniform base + lane*16)
__device__ __forceinline__ void gl16(const ushort* g, ushort* l) {
    __builtin_amdgcn_global_load_lds(
        (__attribute__((address_space(1))) void*)(size_t)(g),
        (__attribute__((address_space(3))) void*)(l), 16, 0, 0);
}

// ---------------- fp32 -> (bf16 hi, bf16 lo) split, RNE ----------------
__device__ __forceinline__ void split1(float x, ushort& h, ushort& l) {
    unsigned b  = __float_as_uint(x);
    unsigned hb = (b + 0x7FFFu + ((b >> 16) & 1u)) >> 16;   // RNE to bf16
    float hf = __uint_as_float(hb << 16);
    float r  = x - hf;
    unsigned rb = __float_as_uint(r);
    unsigned lb = (rb + 0x7FFFu + ((rb >> 16) & 1u)) >> 16;
    h = (ushort)hb; l = (ushort)lb;
}

__device__ __forceinline__ ushort bf16rne(float x) {
    unsigned b = __float_as_uint(x);
    return (ushort)((b + 0x7FFFu + ((b >> 16) & 1u)) >> 16);
}

// ---------------- fused prep: x-split (+hist zero) | Wqkv wsplit | Wout wsplit
__global__ __launch_bounds__(256) void k_prep(
    const float* __restrict__ x, ushort* __restrict__ xh,
    ushort* __restrict__ xl, int n, unsigned* __restrict__ hist,
    const float* __restrict__ Wqkv, ushort* __restrict__ Wqth,
    ushort* __restrict__ Wqtl,
    const float* __restrict__ Wout, ushort* __restrict__ Woth,
    ushort* __restrict__ Wotl) {
    __shared__ float t[64][65];
    int bx = blockIdx.x, tid = threadIdx.x;
    if (bx < 3072) {
        int g = bx * 256 + tid;
        if (g < BH * NBIN) hist[g] = 0u;
        int i = g * 4;
        if (i >= n) return;
        float4 v = *(const float4*)(x + i);
        ushort4 hh, ll;
        split1(v.x, hh.x, ll.x); split1(v.y, hh.y, ll.y);
        split1(v.z, hh.z, ll.z); split1(v.w, hh.w, ll.w);
        *(ushort4*)(xh + i) = hh;
        *(ushort4*)(xl + i) = ll;
        return;
    }
    const float* W; ushort* Wth; ushort* Wtl; int N, n0, k0;
    if (bx < 3504) {
        int b2 = bx - 3072;
        W = Wqkv; Wth = Wqth; Wtl = Wqtl; N = D3;
        n0 = (b2 % 36) * 64; k0 = (b2 / 36) * 64;
    } else {
        int b2 = bx - 3504;
        W = Wout; Wth = Woth; Wtl = Wotl; N = DMODEL;
        n0 = (b2 % 12) * 64; k0 = (b2 / 12) * 64;
    }
    const int K = DMODEL;
    int r = tid >> 4, c = (tid & 15) * 4;
#pragma unroll
    for (int u = 0; u < 4; u++) {
        int rr = r + u * 16;
        float4 v = *(const float4*)(W + (size_t)(k0 + rr) * N + n0 + c);
        t[rr][c] = v.x; t[rr][c + 1] = v.y; t[rr][c + 2] = v.z; t[rr][c + 3] = v.w;
    }
    __syncthreads();
    int nn = tid >> 2, kc = (tid & 3) * 16;
    ushort hb[16] __attribute__((aligned(16)));
    ushort lb[16] __attribute__((aligned(16)));
#pragma unroll
    for (int j = 0; j < 16; j++) split1(t[kc + j][nn], hb[j], lb[j]);
    ushort* dh = Wth + (size_t)(n0 + nn) * K + k0 + kc;
    ushort* dl = Wtl + (size_t)(n0 + nn) * K + k0 + kc;
    *(uint4*)(dh)     = *(uint4*)&hb[0];
    *(uint4*)(dh + 8) = *(uint4*)&hb[8];
    *(uint4*)(dl)     = *(uint4*)&lb[0];
    *(uint4*)(dl + 8) = *(uint4*)&lb[8];
}

// ======================================================================
// bf16x3 GEMM core v2 (r17 best): BM=128, BN=128, BK=32, 256 thr,
// SINGLE-buffered 32 KB LDS, 2 barriers/K-step. Measured best: qkv ~64us.
// Explicit dbuf (r18: 90us, occupancy 17.8->12.9) and s_setprio (r16:
// 75us) both REGRESS this lockstep structure — do not re-add.
// ======================================================================
#define STAGE_LDS(ko)                                                           \
    gl16(gAh + (ko), &sA[0][wbase]);                                            \
    gl16(gAh2 + (ko), &sA[0][2048 + wbase]);                                    \
    gl16(gAl + (ko), &sA[1][wbase]);                                            \
    gl16(gAl2 + (ko), &sA[1][2048 + wbase]);                                    \
    gl16(gBh + (ko), &sB[0][wbase]);                                            \
    gl16(gBh2 + (ko), &sB[0][2048 + wbase]);                                    \
    gl16(gBl + (ko), &sB[1][wbase]);                                            \
    gl16(gBl2 + (ko), &sB[1][2048 + wbase]);

#define GEMM_CORE_SETUP(Kdim)                                                   \
    __shared__ ushort sA[2][128 * 32];                                          \
    __shared__ ushort sB[2][128 * 32];                                          \
    int tid = threadIdx.x, lane = tid & 63, wave = tid >> 6;                    \
    int wm = (wave >> 1) * 64, wn = (wave & 1) * 64;                            \
    int l15 = lane & 15, q = lane >> 4;                                         \
    int sr = tid >> 2, sc = tid & 3;                                            \
    const int K = (Kdim);                                                       \
    int scs = sc ^ ((sr >> 1) & 3);   /* inverse-swizzled source chunk */       \
    const ushort* gAh = Ah + (size_t)(m0 + sr) * K + scs * 8;                   \
    const ushort* gAl = Al + (size_t)(m0 + sr) * K + scs * 8;                   \
    const ushort* gBh = Bh + (size_t)(n0 + sr) * K + scs * 8;                   \
    const ushort* gBl = Bl + (size_t)(n0 + sr) * K + scs * 8;                   \
    const ushort* gAh2 = gAh + (size_t)64 * K;                                  \
    const ushort* gAl2 = gAl + (size_t)64 * K;                                  \
    const ushort* gBh2 = gBh + (size_t)64 * K;                                  \
    const ushort* gBl2 = gBl + (size_t)64 * K;                                  \
    int wbase = wave * 512;           /* 1024 B per wave, lane l -> +16B*l */   \
    f32x4 acc[4][4] = {};                                                       \
    STAGE_LDS(0)                                                                \
    __syncthreads();                                                            \
    const int NIT = K / 32;                                                     \
    for (int it = 0; it < NIT; ++it) {                                          \
        bf16x8 fah[4], fal[4], fbh[4], fbl[4];                                  \
        _Pragma("unroll")                                                       \
        for (int mt = 0; mt < 4; mt++) {                                        \
            int rr = wm + mt * 16 + l15;                                        \
            fah[mt] = *(const bf16x8*)(&sA[0][SWZ(rr, q)]);                     \
            fal[mt] = *(const bf16x8*)(&sA[1][SWZ(rr, q)]);                     \
        }                                                                       \
        _Pragma("unroll")                                                       \
        for (int nt = 0; nt < 4; nt++) {                                        \
            int rr = wn + nt * 16 + l15;                                        \
            fbh[nt] = *(const bf16x8*)(&sB[0][SWZ(rr, q)]);                     \
            fbl[nt] = *(const bf16x8*)(&sB[1][SWZ(rr, q)]);                     \
        }                                                                       \
        __syncthreads();              /* all frag reads done; LDS reusable */   \
        if (it + 1 < NIT) { STAGE_LDS((it + 1) * 32) }                          \
        _Pragma("unroll")                                                       \
        for (int mt = 0; mt < 4; mt++)                                          \
            _Pragma("unroll")                                                   \
            for (int nt = 0; nt < 4; nt++) {                                    \
                acc[mt][nt] = __builtin_amdgcn_mfma_f32_16x16x32_bf16(          \
                    fah[mt], fbh[nt], acc[mt][nt], 0, 0, 0);                    \
                acc[mt][nt] = __builtin_amdgcn_mfma_f32_16x16x32_bf16(          \
                    fah[mt], fbl[nt], acc[mt][nt], 0, 0, 0);                    \
                acc[mt][nt] = __builtin_amdgcn_mfma_f32_16x16x32_bf16(          \
                    fal[mt], fbh[nt], acc[mt][nt], 0, 0, 0);                    \
            }                                                                   \
        __syncthreads();              /* stage drained before next reads */     \
    }

// ---------------- out-proj GEMM: C = A@B + bias (fp32 out) ----------------
// 1D grid 192, XCD-chunked: xcd owns 8m x 3n region (L2 panel reuse).
__global__ __launch_bounds__(256) void k_gemm_out(
    const ushort* __restrict__ Ah, const ushort* __restrict__ Al,
    const ushort* __restrict__ Bh, const ushort* __restrict__ Bl,
    const float* __restrict__ bias, float* __restrict__ C,
    int M, int N, int Kin) {
    int orig = blockIdx.x;
    int xcd = orig & 7, local = orig >> 3;      // 24 blocks per XCD
    int mslab = xcd >> 1, nhalf = xcd & 1;
    int ml = local / 3, nl = local % 3;         // 8m x 3n region
    int m0 = (mslab * 8 + ml) * 128;
    int n0 = (nhalf * 3 + nl) * 128;
    GEMM_CORE_SETUP(Kin)
#pragma unroll
    for (int nt = 0; nt < 4; nt++) {
        int col = n0 + wn + nt * 16 + l15;
        float bv = bias[col];
#pragma unroll
        for (int mt = 0; mt < 4; mt++) {
            int rowb = m0 + wm + mt * 16 + q * 4;
#pragma unroll
            for (int r = 0; r < 4; r++)
                C[(size_t)(rowb + r) * N + col] = acc[mt][nt][r] + bv;
        }
    }
}

// ---------------- QKV GEMM: epilogue writes split Q/K straight + V(hi) transposed
// 1D grid 576, XCD-chunked: xcd owns 8m x 9n region (FETCH 71.8 -> 29.6MB, r17).
__global__ __launch_bounds__(256) void k_gemm_qkv(
    const ushort* __restrict__ Ah, const ushort* __restrict__ Al,
    const ushort* __restrict__ Bh, const ushort* __restrict__ Bl,
    const float* __restrict__ bias,
    ushort* __restrict__ Qh, ushort* __restrict__ Ql,
    ushort* __restrict__ Kh, ushort* __restrict__ Kl,
    ushort* __restrict__ Vth) {
    int orig = blockIdx.x;
    int xcd = orig & 7, local = orig >> 3;      // 72 blocks per XCD
    int mslab = xcd >> 1, nhalf = xcd & 1;
    int ml = local / 9, nl = local % 9;         // 8m x 9n region
    int m0 = (mslab * 8 + ml) * 128;
    int n0 = (nhalf * 9 + nl) * 128;
    GEMM_CORE_SETUP(DMODEL)
    int region = n0 / 768;    // 0=Q, 1=K, 2=V (uniform per block: 128 | 768)
#pragma unroll
    for (int nt = 0; nt < 4; nt++) {
        int col = n0 + wn + nt * 16 + l15;
        float bv = bias[col];
        int cin = col - region * 768;
        int h = cin >> 6, d = cin & 63;
#pragma unroll
        for (int mt = 0; mt < 4; mt++) {
            int rowb = m0 + wm + mt * 16 + q * 4;
            int b = rowb >> 10;
            int s0 = rowb & 1023;
            int bh = b * NHEADS + h;
            if (region == 2) {
                ushort h4[4] __attribute__((aligned(8)));
#pragma unroll
                for (int r = 0; r < 4; r++)
                    h4[r] = bf16rne(acc[mt][nt][r] + bv);
                size_t off = ((size_t)(bh * 64 + d) << 10) + s0;
                *(ushort4*)(Vth + off) = *(ushort4*)h4;
            } else {
                ushort* Ph = region ? Kh : Qh;
                ushort* Pl = region ? Kl : Ql;
                size_t off = ((size_t)((bh << 10) + s0)) * 64 + d;
#pragma unroll
                for (int r = 0; r < 4; r++) {
                    ushort hs, ls;
                    split1(acc[mt][nt][r] + bv, hs, ls);
                    Ph[off + (size_t)r * 64] = hs;
                    Pl[off + (size_t)r * 64] = ls;
                }
            }
        }
    }
}

// ---------------- scores v2: HIST-ONLY, 128-i x 512-j per block ---------------
// grid 768 (XCD-chunked: 8*96, each XCD owns 6 whole bh). Flattened 16-step
// K-pipeline; per-element S accumulation order identical -> threshold bit-exact.
__global__ __launch_bounds__(256) void k_scores(
    const ushort* __restrict__ Qh, const ushort* __restrict__ Ql,
    const ushort* __restrict__ Kh, const ushort* __restrict__ Kl,
    unsigned* __restrict__ hist) {
    __shared__ unsigned lh[NBIN];
    int orig = blockIdx.x;
    int wid = (orig & 7) * 96 + (orig >> 3);   // bijective: 768 = 8*96
    int bh = wid >> 4;
    int rem = wid & 15;
    int i0 = (rem >> 1) * 128;
    int j0b = (rem & 1) * 512;
    int tid = threadIdx.x, lane = tid & 63, wave = tid >> 6;
    int l15 = lane & 15, q = lane >> 4;
    int wj = (wave >> 1) * 64, wi = (wave & 1) * 64;   // j = M-dim, i = N-dim
    for (int i = tid; i < NBIN; i += 256) lh[i] = 0u;
    __syncthreads();   // lh ready; no further block-wide sync until flush

    const ushort* qb  = Qh + ((size_t)bh << 16);
    const ushort* qlb = Ql + ((size_t)bh << 16);
    const ushort* kb  = Kh + ((size_t)bh << 16);
    const ushort* klb = Kl + ((size_t)bh << 16);

    bf16x8 fqh[4][2], fql[4][2];
#pragma unroll
    for (int nt = 0; nt < 4; nt++)
#pragma unroll
        for (int kk = 0; kk < 2; kk++) {
            size_t off = (size_t)(i0 + wi + nt * 16 + l15) * 64 + kk * 32 + q * 8;
            fqh[nt][kk] = *(const bf16x8*)(qb + off);
            fql[nt][kk] = *(const bf16x8*)(qlb + off);
        }
    bf16x8 fkh[2][2], fkl[2][2];
    {   // prologue: step 0's K frags (j-row = j0b + wj)
        size_t off = (size_t)(j0b + wj + l15) * 64 + q * 8;
        fkh[0][0] = *(const bf16x8*)(kb + off);
        fkl[0][0] = *(const bf16x8*)(klb + off);
        fkh[0][1] = *(const bf16x8*)(kb + off + 32);
        fkl[0][1] = *(const bf16x8*)(klb + off + 32);
    }

#pragma unroll
    for (int s = 0; s < 16; s++) {
        int cur = s & 1;
        if (s + 1 < 16) {   // prefetch next step's K frags (crosses j-tiles)
            int s1 = s + 1;
            int jr = j0b + (s1 >> 2) * 128 + wj + (s1 & 3) * 16;
            size_t off = (size_t)(jr + l15) * 64 + q * 8;
            fkh[cur ^ 1][0] = *(const bf16x8*)(kb + off);
            fkl[cur ^ 1][0] = *(const bf16x8*)(klb + off);
            fkh[cur ^ 1][1] = *(const bf16x8*)(kb + off + 32);
            fkl[cur ^ 1][1] = *(const bf16x8*)(klb + off + 32);
        }
        f32x4 acc[4] = {};
        __builtin_amdgcn_s_setprio(1);
#pragma unroll
        for (int kk = 0; kk < 2; kk++)
#pragma unroll
            for (int nt = 0; nt < 4; nt++) {
                acc[nt] = __builtin_amdgcn_mfma_f32_16x16x32_bf16(
                    fkh[cur][kk], fqh[nt][kk], acc[nt], 0, 0, 0);
                acc[nt] = __builtin_amdgcn_mfma_f32_16x16x32_bf16(
                    fkl[cur][kk], fqh[nt][kk], acc[nt], 0, 0, 0);
                acc[nt] = __builtin_amdgcn_mfma_f32_16x16x32_bf16(
                    fkh[cur][kk], fql[nt][kk], acc[nt], 0, 0, 0);
            }
        __builtin_amdgcn_s_setprio(0);
#pragma unroll
        for (int nt = 0; nt < 4; nt++) {
#pragma unroll
            for (int r = 0; r < 4; r++) {
                ushort u = bf16rne(__expf(acc[nt][r] * 0.125f));
                int bin = (int)u - BIN0;
                bin = (bin < 0) ? 0 : ((bin > NBIN - 1) ? NBIN - 1 : bin);
                atomicAdd(&lh[bin], 1u);
            }
        }
    }
    __syncthreads();
    for (int i = tid; i < NBIN; i += 256) {
        unsigned cc = lh[i];
        if (cc) atomicAdd(&hist[bh * NBIN + i], cc);
    }
}

// ---------------- PV fused v5: wave-parallel select + LDS-staged recompute ----
__global__ __launch_bounds__(256) void k_pv(const ushort* __restrict__ Qh,
                                            const ushort* __restrict__ Ql,
                                            const ushort* __restrict__ Kh,
                                            const ushort* __restrict__ Kl,
                                            const ushort* __restrict__ Vth,
                                            const unsigned* __restrict__ hist,
                                            ushort* __restrict__ ctxh,
                                            ushort* __restrict__ ctxl) {
    __shared__ ushort sK[2][2][32 * 64];   // [buf][h/l][32 j][8 swz chunks]
    __shared__ ushort sV[2][64 * 32];      // [buf] GEMM-SWZ [64 d][32 j]
    __shared__ ushort pt[4][32 * 40] __attribute__((aligned(16)));
    __shared__ unsigned wtot[4];
    __shared__ unsigned thrS;
    int orig = blockIdx.x;
    int wid = (orig & 7) * 48 + (orig >> 3);   // bijective: 384 = 8*48
    int bh = wid >> 3;
    int i0 = (wid & 7) * 128;
    int b = bh / NHEADS, h = bh % NHEADS;
    int tid = threadIdx.x, lane = tid & 63, wave = tid >> 6;
    int l15 = lane & 15, q = lane >> 4;

    const ushort* qb  = Qh + ((size_t)bh << 16);
    const ushort* qlb = Ql + ((size_t)bh << 16);
    const ushort* kb  = Kh + ((size_t)bh << 16);
    const ushort* klb = Kl + ((size_t)bh << 16);
    const ushort* vh0 = Vth + ((size_t)bh << 16);   // [64 d][1024 j]

    // staging sources (pre-swizzled); dest is wave-uniform base + lane*16
    int sr2 = tid >> 3, sc2 = tid & 7;   // K tile coords
    const ushort* gK  = kb  + (size_t)sr2 * 64 + ((sc2 ^ (sr2 & 7)) * 8);
    const ushort* gKl = klb + (size_t)sr2 * 64 + ((sc2 ^ (sr2 & 7)) * 8);
    int sr = tid >> 2, sc = tid & 3;     // V tile coords
    const ushort* gV = vh0 + (size_t)sr * 1024 + ((sc ^ ((sr >> 1) & 3)) * 8);
    int wbase = wave * 512;

    // prologue: stage j-window 0 into buf 0 (loads fly during the select scan)
    gl16(gK,  &sK[0][0][wbase]);
    gl16(gKl, &sK[0][1][wbase]);
    gl16(gV,  &sV[0][wbase]);

    // ---- inline select, wave-parallel scan (unsigned adds -> bit-identical)
    const unsigned* hrow = hist + bh * NBIN;
    unsigned psum = 0;
#pragma unroll
    for (int i = 0; i < 16; i++) psum += hrow[tid * 16 + i];
    unsigned incl = psum;
#pragma unroll
    for (int off = 1; off < 64; off <<= 1) {
        unsigned xx = __shfl_up(incl, off, 64);
        if (lane >= off) incl += xx;
    }
    if (lane == 63) wtot[wave] = incl;
    __syncthreads();            // wtot ready (also drains prologue staging)
    unsigned base = 0;
#pragma unroll
    for (int w2 = 0; w2 < 4; w2++)
        if (w2 < wave) base += wtot[w2];
    unsigned pre = base + incl - psum;
    if (pre < KTH && pre + psum >= KTH) {
        unsigned run = pre; int d = 15;
#pragma unroll
        for (int i = 0; i < 16; i++) {
            unsigned v = hrow[tid * 16 + i];
            if (run + v >= KTH) { d = i; break; }
            run += v;
        }
        thrS = (unsigned)(BIN0 + tid * 16 + d);
    }
    __syncthreads();
    unsigned t = thrS;

    // Q frags: 2 i-groups x {kk0,kk1} x {h,l}
    bf16x8 fqh[2][2], fql[2][2];
#pragma unroll
    for (int ig = 0; ig < 2; ig++)
#pragma unroll
        for (int kk = 0; kk < 2; kk++) {
            size_t off = (size_t)(i0 + wave * 32 + ig * 16 + l15) * 64 + kk * 32 + q * 8;
            fqh[ig][kk] = *(const bf16x8*)(qb + off);
            fql[ig][kk] = *(const bf16x8*)(qlb + off);
        }

    f32x4 accp[2][4] = {};
    f32x4 lacc[2] = {};
    uint4 onesu = {0x3F803F80u, 0x3F803F80u, 0x3F803F80u, 0x3F803F80u};
    bf16x8 ones = *(bf16x8*)&onesu;
    ushort* myP = &pt[wave][0];

    for (int j0 = 0; j0 < SEQ; j0 += 32) {
        int cur = (j0 >> 5) & 1;
        // K frags from LDS (swizzled chunk lookup)
        bf16x8 kh[2][2], kl[2][2];   // [j16][kk]
#pragma unroll
        for (int j16 = 0; j16 < 2; j16++) {
            int row = j16 * 16 + l15, rs = row & 7;
#pragma unroll
            for (int kk = 0; kk < 2; kk++) {
                int off = row * 64 + (((kk * 4 + q) ^ rs) * 8);
                kh[j16][kk] = *(const bf16x8*)(&sK[cur][0][off]);
                kl[j16][kk] = *(const bf16x8*)(&sK[cur][1][off]);
            }
        }
        bf16x8 fvh[4];
#pragma unroll
        for (int nt = 0; nt < 4; nt++)
            fvh[nt] = *(const bf16x8*)(&sV[cur][SWZ(nt * 16 + l15, q)]);
        // prefetch next window while computing this one
        if (j0 + 32 < SEQ) {
            int nxt = cur ^ 1;
            gl16(gK  + (size_t)(j0 + 32) * 64, &sK[nxt][0][wbase]);
            gl16(gKl + (size_t)(j0 + 32) * 64, &sK[nxt][1][wbase]);
            gl16(gV  + (j0 + 32),              &sV[nxt][wbase]);
        }
        // QK^T (same order as k_scores) -> exp -> mask -> wave-private P-tile
        __builtin_amdgcn_s_setprio(1);
        bf16x8 pa[2];
#pragma unroll
        for (int ig = 0; ig < 2; ig++) {
#pragma unroll
            for (int j16 = 0; j16 < 2; j16++) {
                f32x4 s = {};
                s = __builtin_amdgcn_mfma_f32_16x16x32_bf16(kh[j16][0], fqh[ig][0], s, 0, 0, 0);
                s = __builtin_amdgcn_mfma_f32_16x16x32_bf16(kl[j16][0], fqh[ig][0], s, 0, 0, 0);
                s = __builtin_amdgcn_mfma_f32_16x16x32_bf16(kh[j16][0], fql[ig][0], s, 0, 0, 0);
                s = __builtin_amdgcn_mfma_f32_16x16x32_bf16(kh[j16][1], fqh[ig][1], s, 0, 0, 0);
                s = __builtin_amdgcn_mfma_f32_16x16x32_bf16(kl[j16][1], fqh[ig][1], s, 0, 0, 0);
                s = __builtin_amdgcn_mfma_f32_16x16x32_bf16(kh[j16][1], fql[ig][1], s, 0, 0, 0);
                unsigned pb[4];
#pragma unroll
                for (int r = 0; r < 4; r++) {
                    unsigned u = bf16rne(__expf(s[r] * 0.125f));
                    pb[r] = (u <= t) ? 0u : u;
                }
                uint2 w;
                w.x = pb[0] | (pb[1] << 16);
                w.y = pb[2] | (pb[3] << 16);
                *(uint2*)(&myP[(ig * 16 + l15) * 40 + j16 * 16 + q * 4]) = w;
            }
            pa[ig] = *(const bf16x8*)(&myP[(ig * 16 + l15) * 40 + q * 8]);
        }
        // PV + rowsum (V frags shared across both i-groups)
#pragma unroll
        for (int ig = 0; ig < 2; ig++) {
#pragma unroll
            for (int nt = 0; nt < 4; nt++)
                accp[ig][nt] = __builtin_amdgcn_mfma_f32_16x16x32_bf16(
                    pa[ig], fvh[nt], accp[ig][nt], 0, 0, 0);
            lacc[ig] = __builtin_amdgcn_mfma_f32_16x16x32_bf16(
                pa[ig], ones, lacc[ig], 0, 0, 0);
        }
        __builtin_amdgcn_s_setprio(0);
        __syncthreads();   // staging drained + all waves done with cur
    }
    // epilogue
#pragma unroll
    for (int ig = 0; ig < 2; ig++)
#pragma unroll
        for (int r = 0; r < 4; r++) {
            int i = i0 + wave * 32 + ig * 16 + q * 4 + r;
            float l = lacc[ig][r];
#pragma unroll
            for (int nt = 0; nt < 4; nt++) {
                int d = nt * 16 + l15;
                ushort hs, ls;
                split1(accp[ig][nt][r] / l, hs, ls);
                size_t off = ((size_t)(b * SEQ + i)) * DMODEL + h * 64 + d;
                ctxh[off] = hs;
                ctxl[off] = ls;
            }
        }
}

extern "C" void kernel_launch(void* const* d_in, const int* in_sizes, int n_in,
                              void* d_out, int out_size, void* d_ws, size_t ws_size,
                              hipStream_t stream) {
    const float* x    = (const float*)d_in[0];
    const float* Wqkv = (const float*)d_in[1];
    const float* bqkv = (const float*)d_in[2];
    const float* Wout = (const float*)d_in[3];
    const float* bout = (const float*)d_in[4];
    float* out = (float*)d_out;

    char* ws = (char*)d_ws;
    // persistent layout
    ushort* Qh  = (ushort*)(ws + 0);                 //  6,291,456
    ushort* Ql  = (ushort*)(ws + 6291456);
    ushort* Kh  = (ushort*)(ws + 12582912);
    ushort* Kl  = (ushort*)(ws + 18874368);
    ushort* Vth = (ushort*)(ws + 25165824);          //  6,291,456 (hi only)
    ushort* ctxh = (ushort*)(ws + 239075328);        //  6,291,456
    ushort* ctxl = (ushort*)(ws + 245366784);        // ends 251,658,240
    unsigned* hist = (unsigned*)(ws + 251658240);    // 48*4096*4 = 786,432
    // scratch (former P region):
    ushort* xh     = (ushort*)(ws + 37748736);                 // ends 44,040,192
    ushort* xl     = (ushort*)(ws + 37748736 + 6291456);       // ends 50,331,648
    ushort* Wqkvth = (ushort*)(ws + 37748736 + 12582912);      // ends 53,870,592
    ushort* Wqkvtl = (ushort*)(ws + 37748736 + 16121856);      // ends 57,409,536
    ushort* Woutth = (ushort*)(ws + 57409536);                 // ends 58,589,184
    ushort* Wouttl = (ushort*)(ws + 58589184);                 // ends 59,768,832

    // fused prep: x split (+hist zero) | Wqkv wsplit | Wout wsplit (1 launch)
    k_prep<<<3648, 256, 0, stream>>>(x, xh, xl, NTOK * DMODEL, hist,
                                     Wqkv, Wqkvth, Wqkvtl, Wout, Woutth, Wouttl);
    k_gemm_qkv<<<576, 256, 0, stream>>>(
        xh, xl, Wqkvth, Wqkvtl, bqkv, Qh, Ql, Kh, Kl, Vth);
    // pass 1: exact 4096-bin histogram of bf16(exp(QK^T/8)) — no P store
    k_scores<<<768, 256, 0, stream>>>(Qh, Ql, Kh, Kl, hist);
    // pass 2: fused select + recompute QK^T -> exp -> mask -> PV / rowsum
    k_pv<<<384, 256, 0, stream>>>(Qh, Ql, Kh, Kl, Vth, hist, ctxh, ctxl);
    // out = ctx @ W_out + b_out
    k_gemm_out<<<192, 256, 0, stream>>>(
        ctxh, ctxl, Woutth, Wouttl, bout, out, NTOK, DMODEL, DMODEL);
}